// Round 5
// baseline (430.910 us; speedup 1.0000x reference)
//
#include <hip/hip_runtime.h>
#include <cstddef>

typedef short short8 __attribute__((ext_vector_type(8)));
typedef float f32x4 __attribute__((ext_vector_type(4)));

#define SS 1024
#define NH 16
#define DH 64
#define NB 4

static __device__ __forceinline__ unsigned short f2bf(float f) {
    union { float f; unsigned int i; } x; x.f = f;
    unsigned int r = x.i + 0x7FFFu + ((x.i >> 16) & 1u);
    return (unsigned short)(r >> 16);
}
static __device__ __forceinline__ float bf2f(unsigned short u) {
    union { unsigned int i; float f; } x; x.i = ((unsigned int)u) << 16;
    return x.f;
}

// async global->LDS 16B copy. Per-wave: lane l's lds ptr must be base + l*16.
static __device__ __forceinline__ void g2l16(const void* g, void* l) {
    __builtin_amdgcn_global_load_lds(
        (const __attribute__((address_space(1))) unsigned int*)g,
        (__attribute__((address_space(3))) unsigned int*)l, 16, 0, 0);
}

// ---------------- prep: cast m_feats -> bf16  ++  transpose-cast weights ----------------
// blocks [0,2048): cast m_feats (4096x1024 fp32 -> bf16), 8 elems/thread
// blocks [2048,5120): transpose W_v (1024x1024) ++ W_c (1024x2048) -> WT bf16 [3072][1024]
__global__ __launch_bounds__(256) void prep(const float* __restrict__ mf,
                                            unsigned short* __restrict__ mfb,
                                            const float* __restrict__ Wv,
                                            const float* __restrict__ Wc,
                                            unsigned short* __restrict__ WT) {
    __shared__ float tile[32][33];
    int bx = blockIdx.x;
    int t = threadIdx.x;
    if (bx < 2048) {
        size_t i = ((size_t)bx * 256 + t) * 8;
        float4 v0 = *(const float4*)(mf + i);
        float4 v1 = *(const float4*)(mf + i + 4);
        short8 o;
        o[0] = (short)f2bf(v0.x); o[1] = (short)f2bf(v0.y);
        o[2] = (short)f2bf(v0.z); o[3] = (short)f2bf(v0.w);
        o[4] = (short)f2bf(v1.x); o[5] = (short)f2bf(v1.y);
        o[6] = (short)f2bf(v1.z); o[7] = (short)f2bf(v1.w);
        *(short8*)(mfb + i) = o;
        return;
    }
    bx -= 2048;
    int n0 = (bx % 96) * 32, k0 = (bx / 96) * 32;
    int kr = t >> 3, nc = (t & 7) * 4;
    const float* src; int ld; int nn = n0 + nc;
    if (n0 < 1024) { src = Wv; ld = 1024; } else { src = Wc; ld = 2048; nn -= 1024; }
    float4 v = *(const float4*)(src + (size_t)(k0 + kr) * ld + nn);
    tile[kr][nc + 0] = v.x; tile[kr][nc + 1] = v.y;
    tile[kr][nc + 2] = v.z; tile[kr][nc + 3] = v.w;
    __syncthreads();
    int nr = t >> 3, kc = (t & 7) * 4;
    short4 o;
    o.x = (short)f2bf(tile[kc + 0][nr]); o.y = (short)f2bf(tile[kc + 1][nr]);
    o.z = (short)f2bf(tile[kc + 2][nr]); o.w = (short)f2bf(tile[kc + 3][nr]);
    *(short4*)(WT + (size_t)(n0 + nr) * 1024 + k0 + kc) = o;
}

// ---------------- GEMM: C[4096][3072] = A[4096][1024] * BT ----------------
// cols 0..2047 -> kq row-major; cols 2048..3071 -> mvT scattered to [b][h][d][j]
// v4: double-buffered LDS, stage-before-compute, ONE barrier per K-step
// (T3-minimum 2-phase: stage latency overlaps MFMA of previous tile).
__global__ __launch_bounds__(256) void gemm_kqv(const unsigned short* __restrict__ A,
                                                const unsigned short* __restrict__ BT,
                                                const float* __restrict__ bv,
                                                const float* __restrict__ bc,
                                                unsigned short* __restrict__ kq,
                                                unsigned short* __restrict__ mvT) {
    __shared__ __align__(16) unsigned short As[2][128 * 32];
    __shared__ __align__(16) unsigned short Bs[2][128 * 32];
    // XCD-chunked 2x4 swizzle: 768 blocks, 8 XCDs, 96 blocks each (12x of n, 8y of m)
    int lin = blockIdx.y * 24 + blockIdx.x;
    int xcd = lin & 7, idx = lin >> 3;
    int cx = xcd & 1, cy = xcd >> 1;
    int xi = idx % 12, yi = idx / 12;
    int n0 = (cx * 12 + xi) * 128;
    int m0 = (cy * 8 + yi) * 128;

    int tid = threadIdx.x, lane = tid & 63, wv = tid >> 6;
    int wm = wv >> 1, wn = wv & 1;
    int lq = lane & 15, quad = lane >> 4;

    f32x4 zero = {0.f, 0.f, 0.f, 0.f};
    f32x4 acc[4][4];
#pragma unroll
    for (int i = 0; i < 4; ++i)
#pragma unroll
        for (int j = 0; j < 4; ++j) acc[i][j] = zero;

    // staging decode for the two issues per matrix
    int r0 = tid >> 2, s0 = tid & 3;
    int c0 = s0 ^ ((r0 >> 1) & 3);
    int r1 = (tid + 256) >> 2, s1 = tid & 3;
    int c1 = s1 ^ ((r1 >> 1) & 3);

    const unsigned short* Abase0 = A + (size_t)(m0 + r0) * 1024 + c0 * 8;
    const unsigned short* Abase1 = A + (size_t)(m0 + r1) * 1024 + c1 * 8;
    const unsigned short* Bbase0 = BT + (size_t)(n0 + r0) * 1024 + c0 * 8;
    const unsigned short* Bbase1 = BT + (size_t)(n0 + r1) * 1024 + c1 * 8;

    // prologue: stage tile 0 into buffer 0
    g2l16(Abase0, As[0] + tid * 8);
    g2l16(Abase1, As[0] + (tid + 256) * 8);
    g2l16(Bbase0, Bs[0] + tid * 8);
    g2l16(Bbase1, Bs[0] + (tid + 256) * 8);
    __syncthreads();  // drains vmcnt(0): buffer 0 ready

#pragma unroll 2
    for (int t32 = 0; t32 < 32; ++t32) {
        int cur = t32 & 1;
        if (t32 < 31) {
            int nkt = (t32 + 1) * 32;
            g2l16(Abase0 + nkt, As[cur ^ 1] + tid * 8);
            g2l16(Abase1 + nkt, As[cur ^ 1] + (tid + 256) * 8);
            g2l16(Bbase0 + nkt, Bs[cur ^ 1] + tid * 8);
            g2l16(Bbase1 + nkt, Bs[cur ^ 1] + (tid + 256) * 8);
        }

        short8 af[4], bfr[4];
#pragma unroll
        for (int i = 0; i < 4; ++i) {
            int Ra = wm * 64 + i * 16 + lq;
            af[i] = *(const short8*)(As[cur] + Ra * 32 + (quad ^ ((Ra >> 1) & 3)) * 8);
            int Rb = wn * 64 + i * 16 + lq;
            bfr[i] = *(const short8*)(Bs[cur] + Rb * 32 + (quad ^ ((Rb >> 1) & 3)) * 8);
        }
#pragma unroll
        for (int mi = 0; mi < 4; ++mi)
#pragma unroll
            for (int ni = 0; ni < 4; ++ni)
                acc[mi][ni] = __builtin_amdgcn_mfma_f32_16x16x32_bf16(af[mi], bfr[ni], acc[mi][ni], 0, 0, 0);

        __syncthreads();  // all readers done with cur; next buffer's loads landed
    }

    // epilogue: bias + store (C layout: row = quad*4+reg, col = lq)
#pragma unroll
    for (int mi = 0; mi < 4; ++mi) {
#pragma unroll
        for (int ni = 0; ni < 4; ++ni) {
            int colg = n0 + wn * 64 + ni * 16 + lq;
            float bias = (colg < 1024) ? bv[colg] : bc[colg - 1024];
            if (colg < 2048) {
#pragma unroll
                for (int r = 0; r < 4; ++r) {
                    int rowg = m0 + wm * 64 + mi * 16 + quad * 4 + r;
                    kq[(size_t)rowg * 2048 + colg] = f2bf(acc[mi][ni][r] + bias);
                }
            } else {
                // scatter directly into mvT[b][h][d][j]  (block-uniform branch)
                int c = colg - 2048;           // [0,1024)
                int hh = c >> 6, dd = c & 63;  // head, dim
#pragma unroll
                for (int r = 0; r < 4; ++r) {
                    int rowg = m0 + wm * 64 + mi * 16 + quad * 4 + r;
                    int bb = rowg >> 10, jj = rowg & 1023;
                    mvT[((size_t)(bb * NH + hh) * DH + dd) * 1024 + jj] =
                        f2bf(acc[mi][ni][r] + bias);
                }
            }
        }
    }
}

// ---------------- fused attention ----------------
// v5: identical to v4 EXCEPT output stores are regular cached stores
// (A/B isolation: NT stores bypass L2 and may throttle the write drain;
// read working set is tiny vs 256MB L3, so cached stores are safe).
__global__ __launch_bounds__(256, 4) void attn_kernel(const unsigned short* __restrict__ kq,
                                                      const unsigned short* __restrict__ mvT,
                                                      const int* __restrict__ mask,
                                                      const float* __restrict__ m_feats,
                                                      float* __restrict__ out0,
                                                      float* __restrict__ out1) {
    __shared__ __align__(16) unsigned short mk_s[16 * 72];
    __shared__ __align__(16) unsigned short s_exp[16 * 1032];
    __shared__ float wsum[4][16];
    __shared__ float inv_s[16];

    int tid = threadIdx.x;
    int lane = tid & 63, wv = tid >> 6;
    int lq = lane & 15, quad = lane >> 4;

    // XCD swizzle: 4096 blocks, 8 XCDs -> XCD x gets contiguous chunk of 512
    int blk = ((int)blockIdx.x & 7) * 512 + ((int)blockIdx.x >> 3);
    int it = blk & 63;
    int bh = blk >> 6;
    int h = bh & (NH - 1), b = bh >> 4;
    int i0 = it * 16;

    const float SC = 0.18033688011112042f;  // log2(e)/8
    const unsigned short* mqb = kq + (size_t)b * SS * 2048 + 1024 + h * 64 + quad * 8;
    const int* maskb = mask + (size_t)b * SS;

    short8 qb[2][4][2];
    int qm[2][4];
    float sums[4] = {0.f, 0.f, 0.f, 0.f};

#define QLOAD(p, s)                                                          \
    {                                                                        \
        int jb_ = (s) * 256 + wv * 64;                                       \
        _Pragma("unroll") for (int js = 0; js < 4; ++js) {                   \
            int jg_ = jb_ + js * 16 + lq;                                    \
            size_t ro_ = (size_t)jg_ * 2048;                                 \
            qb[p][js][0] = *(const short8*)(mqb + ro_);                      \
            qb[p][js][1] = *(const short8*)(mqb + ro_ + 32);                 \
            qm[p][js] = maskb[jg_];                                          \
        }                                                                    \
    }

#define QCOMP(p, s)                                                          \
    {                                                                        \
        int jb_ = (s) * 256 + wv * 64;                                       \
        _Pragma("unroll") for (int js = 0; js < 4; ++js) {                   \
            f32x4 acc = {0.f, 0.f, 0.f, 0.f};                                \
            acc = __builtin_amdgcn_mfma_f32_16x16x32_bf16(a0, qb[p][js][0], acc, 0, 0, 0); \
            acc = __builtin_amdgcn_mfma_f32_16x16x32_bf16(a1, qb[p][js][1], acc, 0, 0, 0); \
            int jc_ = jb_ + js * 16 + lq;                                    \
            _Pragma("unroll") for (int r = 0; r < 4; ++r) {                  \
                float e = qm[p][js] ? __builtin_amdgcn_exp2f(acc[r] * SC) : 0.f; \
                sums[r] += e;                                                \
                s_exp[(quad * 4 + r) * 1032 + jc_] = f2bf(e);                \
            }                                                                \
        }                                                                    \
    }

    // hoisted: QK group-0/1 loads in flight before/through the staging barrier
    QLOAD(0, 0);

    // m_feats prefetch for the out0 epilogue (4 scalar f32, L2-cached)
    float mf4[4];
#pragma unroll
    for (int r = 0; r < 4; ++r) {
        size_t o = (size_t)(b * SS + i0 + quad * 4 + r) * 1024 + h * 64 + wv * 16 + lq;
        mf4[r] = m_feats[o];
    }

    if (tid < 128) {
        int row = tid >> 3, ch = tid & 7;
        int4 v = *(const int4*)(kq + (size_t)(b * SS + i0 + row) * 2048 + h * 64 + ch * 8);
        *(int4*)(mk_s + row * 72 + ch * 8) = v;
    }
    QLOAD(1, 1);
    __syncthreads();

    short8 a0 = *(const short8*)(mk_s + lq * 72 + 0 * 32 + quad * 8);
    short8 a1 = *(const short8*)(mk_s + lq * 72 + 1 * 32 + quad * 8);

    QCOMP(0, 0); QLOAD(0, 2);
    QCOMP(1, 1); QLOAD(1, 3);
    QCOMP(0, 2);
    QCOMP(1, 3);
#undef QLOAD
#undef QCOMP

    // ---- PV fragment pipeline state (loads are independent of softmax ->
    // issue them NOW so mvT latency hides under reduce + barriers)
    f32x4 racc = {0.f, 0.f, 0.f, 0.f};
    const unsigned short* mvb = mvT + ((size_t)bh * DH + wv * 16 + lq) * 1024 + quad * 8;
    size_t wbase = ((size_t)bh * SS + i0) * SS;
    short8 vbuf[4][4];

#define VLOAD(p, ko)                                                         \
    {                                                                        \
        _Pragma("unroll") for (int k2 = 0; k2 < 4; ++k2)                     \
            vbuf[p][k2] = *(const short8*)(mvb + ((ko) * 4 + k2) * 32);      \
    }

#define VCOMP(p, ko)                                                         \
    {                                                                        \
        _Pragma("unroll") for (int k2 = 0; k2 < 4; ++k2) {                   \
            short8 ae = *(const short8*)(s_exp + lq * 1032 + ((ko) * 4 + k2) * 32 + quad * 8); \
            racc = __builtin_amdgcn_mfma_f32_16x16x32_bf16(ae, vbuf[p][k2], racc, 0, 0, 0); \
        }                                                                    \
    }

#define WOUT(r)                                                              \
    {                                                                        \
        float iv = inv_s[r];                                                 \
        short4 ev = *(const short4*)(s_exp + (r) * 1032 + tid * 4);          \
        f32x4 wo;                                                            \
        wo[0] = bf2f((unsigned short)ev.x) * iv;                             \
        wo[1] = bf2f((unsigned short)ev.y) * iv;                             \
        wo[2] = bf2f((unsigned short)ev.z) * iv;                             \
        wo[3] = bf2f((unsigned short)ev.w) * iv;                             \
        *(f32x4*)(out1 + wbase + (size_t)(r) * SS + tid * 4) = wo;           \
    }

    VLOAD(0, 0); VLOAD(1, 1);

#pragma unroll
    for (int r = 0; r < 4; ++r) {
        float s = sums[r];
        s += __shfl_xor(s, 1); s += __shfl_xor(s, 2);
        s += __shfl_xor(s, 4); s += __shfl_xor(s, 8);
        if (lq == 0) wsum[wv][quad * 4 + r] = s;
    }
    __syncthreads();
    if (tid < 16) {
        float s = wsum[0][tid] + wsum[1][tid] + wsum[2][tid] + wsum[3][tid];
        inv_s[tid] = 1.0f / s;
    }
    VLOAD(2, 2); VLOAD(3, 3);
    __syncthreads();

    // ---- PV phase: rotation with w-output rows interleaved ----
    VCOMP(0, 0); VLOAD(0, 4); WOUT(0);  WOUT(1);
    VCOMP(1, 1); VLOAD(1, 5); WOUT(2);  WOUT(3);
    VCOMP(2, 2); VLOAD(2, 6); WOUT(4);  WOUT(5);
    VCOMP(3, 3); VLOAD(3, 7); WOUT(6);  WOUT(7);
    VCOMP(0, 4); WOUT(8);  WOUT(9);
    VCOMP(1, 5); WOUT(10); WOUT(11);
    VCOMP(2, 6); WOUT(12); WOUT(13);
    VCOMP(3, 7); WOUT(14); WOUT(15);
#undef VLOAD
#undef VCOMP
#undef WOUT

#pragma unroll
    for (int r = 0; r < 4; ++r) {
        int row = quad * 4 + r;
        size_t o = (size_t)(b * SS + i0 + row) * 1024 + h * 64 + wv * 16 + lq;
        out0[o] = mf4[r] + racc[r] * inv_s[row];
    }
}

extern "C" void kernel_launch(void* const* d_in, const int* in_sizes, int n_in,
                              void* d_out, int out_size, void* d_ws, size_t ws_size,
                              hipStream_t stream) {
    const float* m_feats = (const float*)d_in[0];
    const int*   mask    = (const int*)d_in[1];
    const float* W_c     = (const float*)d_in[2];
    const float* b_c     = (const float*)d_in[3];
    const float* W_v     = (const float*)d_in[4];
    const float* b_v     = (const float*)d_in[5];

    float* out0 = (float*)d_out;                       // updated_m: 4*1024*1024
    float* out1 = out0 + (size_t)NB * SS * 1024;       // w: 4*16*1024*1024

    unsigned short* mf_bf = (unsigned short*)d_ws;                 // 4096*1024
    unsigned short* WT    = mf_bf + (size_t)4096 * 1024;           // 3072*1024
    unsigned short* kq    = WT + (size_t)3072 * 1024;              // 4096*2048
    unsigned short* mvT   = kq + (size_t)4096 * 2048;              // 4096*1024 [b][h][d][j]

    prep<<<dim3(5120), dim3(256), 0, stream>>>(m_feats, mf_bf, W_v, W_c, WT);
    gemm_kqv<<<dim3(24, 32), dim3(256), 0, stream>>>(mf_bf, WT, b_v, b_c, kq, mvT);
    attn_kernel<<<dim3(4096), dim3(256), 0, stream>>>(kq, mvT, mask, m_feats, out0, out1);
}

// Round 6
// 374.353 us; speedup vs baseline: 1.1511x; 1.1511x over previous
//
#include <hip/hip_runtime.h>
#include <cstddef>

typedef short short8 __attribute__((ext_vector_type(8)));
typedef float f32x4 __attribute__((ext_vector_type(4)));

#define SS 1024
#define NH 16
#define DH 64
#define NB 4

static __device__ __forceinline__ unsigned short f2bf(float f) {
    union { float f; unsigned int i; } x; x.f = f;
    unsigned int r = x.i + 0x7FFFu + ((x.i >> 16) & 1u);
    return (unsigned short)(r >> 16);
}
static __device__ __forceinline__ float bf2f(unsigned short u) {
    union { unsigned int i; float f; } x; x.i = ((unsigned int)u) << 16;
    return x.f;
}

// async global->LDS 16B copy. Per-wave: lane l's lds ptr must be base + l*16.
static __device__ __forceinline__ void g2l16(const void* g, void* l) {
    __builtin_amdgcn_global_load_lds(
        (const __attribute__((address_space(1))) unsigned int*)g,
        (__attribute__((address_space(3))) unsigned int*)l, 16, 0, 0);
}

// ---------------- prep: cast m_feats -> bf16  ++  transpose-cast weights ----------------
// blocks [0,2048): cast m_feats (4096x1024 fp32 -> bf16), 8 elems/thread
// blocks [2048,5120): transpose W_v (1024x1024) ++ W_c (1024x2048) -> WT bf16 [3072][1024]
__global__ __launch_bounds__(256) void prep(const float* __restrict__ mf,
                                            unsigned short* __restrict__ mfb,
                                            const float* __restrict__ Wv,
                                            const float* __restrict__ Wc,
                                            unsigned short* __restrict__ WT) {
    __shared__ float tile[32][33];
    int bx = blockIdx.x;
    int t = threadIdx.x;
    if (bx < 2048) {
        size_t i = ((size_t)bx * 256 + t) * 8;
        float4 v0 = *(const float4*)(mf + i);
        float4 v1 = *(const float4*)(mf + i + 4);
        short8 o;
        o[0] = (short)f2bf(v0.x); o[1] = (short)f2bf(v0.y);
        o[2] = (short)f2bf(v0.z); o[3] = (short)f2bf(v0.w);
        o[4] = (short)f2bf(v1.x); o[5] = (short)f2bf(v1.y);
        o[6] = (short)f2bf(v1.z); o[7] = (short)f2bf(v1.w);
        *(short8*)(mfb + i) = o;
        return;
    }
    bx -= 2048;
    int n0 = (bx % 96) * 32, k0 = (bx / 96) * 32;
    int kr = t >> 3, nc = (t & 7) * 4;
    const float* src; int ld; int nn = n0 + nc;
    if (n0 < 1024) { src = Wv; ld = 1024; } else { src = Wc; ld = 2048; nn -= 1024; }
    float4 v = *(const float4*)(src + (size_t)(k0 + kr) * ld + nn);
    tile[kr][nc + 0] = v.x; tile[kr][nc + 1] = v.y;
    tile[kr][nc + 2] = v.z; tile[kr][nc + 3] = v.w;
    __syncthreads();
    int nr = t >> 3, kc = (t & 7) * 4;
    short4 o;
    o.x = (short)f2bf(tile[kc + 0][nr]); o.y = (short)f2bf(tile[kc + 1][nr]);
    o.z = (short)f2bf(tile[kc + 2][nr]); o.w = (short)f2bf(tile[kc + 3][nr]);
    *(short4*)(WT + (size_t)(n0 + nr) * 1024 + k0 + kc) = o;
}

// ---------------- GEMM: C[4096][3072] = A[4096][1024] * BT ----------------
// cols 0..2047 -> kq row-major; cols 2048..3071 -> mvT scattered to [b][h][d][j]
// v4: double-buffered LDS, stage-before-compute, ONE barrier per K-step.
__global__ __launch_bounds__(256) void gemm_kqv(const unsigned short* __restrict__ A,
                                                const unsigned short* __restrict__ BT,
                                                const float* __restrict__ bv,
                                                const float* __restrict__ bc,
                                                unsigned short* __restrict__ kq,
                                                unsigned short* __restrict__ mvT) {
    __shared__ __align__(16) unsigned short As[2][128 * 32];
    __shared__ __align__(16) unsigned short Bs[2][128 * 32];
    // XCD-chunked 2x4 swizzle: 768 blocks, 8 XCDs, 96 blocks each (12x of n, 8y of m)
    int lin = blockIdx.y * 24 + blockIdx.x;
    int xcd = lin & 7, idx = lin >> 3;
    int cx = xcd & 1, cy = xcd >> 1;
    int xi = idx % 12, yi = idx / 12;
    int n0 = (cx * 12 + xi) * 128;
    int m0 = (cy * 8 + yi) * 128;

    int tid = threadIdx.x, lane = tid & 63, wv = tid >> 6;
    int wm = wv >> 1, wn = wv & 1;
    int lq = lane & 15, quad = lane >> 4;

    f32x4 zero = {0.f, 0.f, 0.f, 0.f};
    f32x4 acc[4][4];
#pragma unroll
    for (int i = 0; i < 4; ++i)
#pragma unroll
        for (int j = 0; j < 4; ++j) acc[i][j] = zero;

    // staging decode for the two issues per matrix
    int r0 = tid >> 2, s0 = tid & 3;
    int c0 = s0 ^ ((r0 >> 1) & 3);
    int r1 = (tid + 256) >> 2, s1 = tid & 3;
    int c1 = s1 ^ ((r1 >> 1) & 3);

    const unsigned short* Abase0 = A + (size_t)(m0 + r0) * 1024 + c0 * 8;
    const unsigned short* Abase1 = A + (size_t)(m0 + r1) * 1024 + c1 * 8;
    const unsigned short* Bbase0 = BT + (size_t)(n0 + r0) * 1024 + c0 * 8;
    const unsigned short* Bbase1 = BT + (size_t)(n0 + r1) * 1024 + c1 * 8;

    // prologue: stage tile 0 into buffer 0
    g2l16(Abase0, As[0] + tid * 8);
    g2l16(Abase1, As[0] + (tid + 256) * 8);
    g2l16(Bbase0, Bs[0] + tid * 8);
    g2l16(Bbase1, Bs[0] + (tid + 256) * 8);
    __syncthreads();  // drains vmcnt(0): buffer 0 ready

#pragma unroll 2
    for (int t32 = 0; t32 < 32; ++t32) {
        int cur = t32 & 1;
        if (t32 < 31) {
            int nkt = (t32 + 1) * 32;
            g2l16(Abase0 + nkt, As[cur ^ 1] + tid * 8);
            g2l16(Abase1 + nkt, As[cur ^ 1] + (tid + 256) * 8);
            g2l16(Bbase0 + nkt, Bs[cur ^ 1] + tid * 8);
            g2l16(Bbase1 + nkt, Bs[cur ^ 1] + (tid + 256) * 8);
        }

        short8 af[4], bfr[4];
#pragma unroll
        for (int i = 0; i < 4; ++i) {
            int Ra = wm * 64 + i * 16 + lq;
            af[i] = *(const short8*)(As[cur] + Ra * 32 + (quad ^ ((Ra >> 1) & 3)) * 8);
            int Rb = wn * 64 + i * 16 + lq;
            bfr[i] = *(const short8*)(Bs[cur] + Rb * 32 + (quad ^ ((Rb >> 1) & 3)) * 8);
        }
#pragma unroll
        for (int mi = 0; mi < 4; ++mi)
#pragma unroll
            for (int ni = 0; ni < 4; ++ni)
                acc[mi][ni] = __builtin_amdgcn_mfma_f32_16x16x32_bf16(af[mi], bfr[ni], acc[mi][ni], 0, 0, 0);

        __syncthreads();  // all readers done with cur; next buffer's loads landed
    }

    // epilogue: bias + store (C layout: row = quad*4+reg, col = lq)
#pragma unroll
    for (int mi = 0; mi < 4; ++mi) {
#pragma unroll
        for (int ni = 0; ni < 4; ++ni) {
            int colg = n0 + wn * 64 + ni * 16 + lq;
            float bias = (colg < 1024) ? bv[colg] : bc[colg - 1024];
            if (colg < 2048) {
#pragma unroll
                for (int r = 0; r < 4; ++r) {
                    int rowg = m0 + wm * 64 + mi * 16 + quad * 4 + r;
                    kq[(size_t)rowg * 2048 + colg] = f2bf(acc[mi][ni][r] + bias);
                }
            } else {
                // scatter directly into mvT[b][h][d][j]  (block-uniform branch)
                int c = colg - 2048;           // [0,1024)
                int hh = c >> 6, dd = c & 63;  // head, dim
#pragma unroll
                for (int r = 0; r < 4; ++r) {
                    int rowg = m0 + wm * 64 + mi * 16 + quad * 4 + r;
                    int bb = rowg >> 10, jj = rowg & 1023;
                    mvT[((size_t)(bb * NH + hh) * DH + dd) * 1024 + jj] =
                        f2bf(acc[mi][ni][r] + bias);
                }
            }
        }
    }
}

// ---------------- fused attention ----------------
// v6: 32 i-rows per block (2048 blocks). Each j-load feeds TWO i-tiles:
// QK does 4 MFMAs per qb pair (2x AI), PV reuses each vbuf for 2 racc sets.
// L2 read traffic halves. LDS ~71KB -> 2 blocks/CU. NT stores restored.
__global__ __launch_bounds__(256, 2) void attn_kernel(const unsigned short* __restrict__ kq,
                                                      const unsigned short* __restrict__ mvT,
                                                      const int* __restrict__ mask,
                                                      const float* __restrict__ m_feats,
                                                      float* __restrict__ out0,
                                                      float* __restrict__ out1) {
    __shared__ __align__(16) unsigned short mk_s[32 * 72];
    __shared__ __align__(16) unsigned short s_exp[32 * 1032];
    __shared__ float wsum[4][32];
    __shared__ float inv_s[32];

    int tid = threadIdx.x;
    int lane = tid & 63, wv = tid >> 6;
    int lq = lane & 15, quad = lane >> 4;

    // XCD swizzle: 2048 blocks, 8 XCDs -> XCD x gets contiguous chunk of 256
    int blk = ((int)blockIdx.x & 7) * 256 + ((int)blockIdx.x >> 3);
    int it = blk & 31;
    int bh = blk >> 5;
    int h = bh & (NH - 1), b = bh >> 4;
    int i0 = it * 32;

    const float SC = 0.18033688011112042f;  // log2(e)/8
    const unsigned short* mqb = kq + (size_t)b * SS * 2048 + 1024 + h * 64 + quad * 8;
    const int* maskb = mask + (size_t)b * SS;

    short8 qb[2][4][2];
    int qm[2][4];
    float sums[2][4] = {{0.f, 0.f, 0.f, 0.f}, {0.f, 0.f, 0.f, 0.f}};

#define QLOAD(p, s)                                                          \
    {                                                                        \
        int jb_ = (s) * 256 + wv * 64;                                       \
        _Pragma("unroll") for (int js = 0; js < 4; ++js) {                   \
            int jg_ = jb_ + js * 16 + lq;                                    \
            size_t ro_ = (size_t)jg_ * 2048;                                 \
            qb[p][js][0] = *(const short8*)(mqb + ro_);                      \
            qb[p][js][1] = *(const short8*)(mqb + ro_ + 32);                 \
            qm[p][js] = maskb[jg_];                                          \
        }                                                                    \
    }

// per j-subtile: 2 i-tiles x 2 MFMAs, exp+store for both
#define QCOMP(p, s)                                                          \
    {                                                                        \
        int jb_ = (s) * 256 + wv * 64;                                       \
        _Pragma("unroll") for (int js = 0; js < 4; ++js) {                   \
            int jc_ = jb_ + js * 16 + lq;                                    \
            _Pragma("unroll") for (int ti = 0; ti < 2; ++ti) {               \
                f32x4 acc = {0.f, 0.f, 0.f, 0.f};                            \
                acc = __builtin_amdgcn_mfma_f32_16x16x32_bf16(a[ti][0], qb[p][js][0], acc, 0, 0, 0); \
                acc = __builtin_amdgcn_mfma_f32_16x16x32_bf16(a[ti][1], qb[p][js][1], acc, 0, 0, 0); \
                _Pragma("unroll") for (int r = 0; r < 4; ++r) {              \
                    float e = qm[p][js] ? __builtin_amdgcn_exp2f(acc[r] * SC) : 0.f; \
                    sums[ti][r] += e;                                        \
                    s_exp[(ti * 16 + quad * 4 + r) * 1032 + jc_] = f2bf(e);  \
                }                                                            \
            }                                                                \
        }                                                                    \
    }

    // hoisted: QK group-0/1 loads in flight before/through the staging barrier
    QLOAD(0, 0);

    // m_feats prefetch for the out0 epilogue
    float mf8[2][4];
#pragma unroll
    for (int ti = 0; ti < 2; ++ti)
#pragma unroll
        for (int r = 0; r < 4; ++r) {
            size_t o = (size_t)(b * SS + i0 + ti * 16 + quad * 4 + r) * 1024 + h * 64 + wv * 16 + lq;
            mf8[ti][r] = m_feats[o];
        }

    // stage mk: 32 rows x 64 shorts, 8 threads/row x int4
    {
        int row = tid >> 3, ch = tid & 7;
        int4 v = *(const int4*)(kq + (size_t)(b * SS + i0 + row) * 2048 + h * 64 + ch * 8);
        *(int4*)(mk_s + row * 72 + ch * 8) = v;
    }
    QLOAD(1, 1);
    __syncthreads();

    short8 a[2][2];
#pragma unroll
    for (int ti = 0; ti < 2; ++ti) {
        a[ti][0] = *(const short8*)(mk_s + (ti * 16 + lq) * 72 + 0 * 32 + quad * 8);
        a[ti][1] = *(const short8*)(mk_s + (ti * 16 + lq) * 72 + 1 * 32 + quad * 8);
    }

    QCOMP(0, 0); QLOAD(0, 2);
    QCOMP(1, 1); QLOAD(1, 3);
    QCOMP(0, 2);
    QCOMP(1, 3);
#undef QLOAD
#undef QCOMP

    // ---- PV pipeline state: loads independent of softmax -> issue now
    f32x4 racc[2] = {{0.f, 0.f, 0.f, 0.f}, {0.f, 0.f, 0.f, 0.f}};
    const unsigned short* mvb = mvT + ((size_t)bh * DH + wv * 16 + lq) * 1024 + quad * 8;
    size_t wbase = ((size_t)bh * SS + i0) * SS;
    short8 vbuf[4][4];

#define VLOAD(p, ko)                                                         \
    {                                                                        \
        _Pragma("unroll") for (int k2 = 0; k2 < 4; ++k2)                     \
            vbuf[p][k2] = *(const short8*)(mvb + ((ko) * 4 + k2) * 32);      \
    }

// each vbuf fragment feeds BOTH i-tiles' accumulators
#define VCOMP(p, ko)                                                         \
    {                                                                        \
        _Pragma("unroll") for (int k2 = 0; k2 < 4; ++k2) {                   \
            _Pragma("unroll") for (int ti = 0; ti < 2; ++ti) {               \
                short8 ae = *(const short8*)(s_exp + (ti * 16 + lq) * 1032 + ((ko) * 4 + k2) * 32 + quad * 8); \
                racc[ti] = __builtin_amdgcn_mfma_f32_16x16x32_bf16(ae, vbuf[p][k2], racc[ti], 0, 0, 0); \
            }                                                                \
        }                                                                    \
    }

#define WOUT(r)                                                              \
    {                                                                        \
        float iv = inv_s[r];                                                 \
        short4 ev = *(const short4*)(s_exp + (r) * 1032 + tid * 4);          \
        f32x4 wo;                                                            \
        wo[0] = bf2f((unsigned short)ev.x) * iv;                             \
        wo[1] = bf2f((unsigned short)ev.y) * iv;                             \
        wo[2] = bf2f((unsigned short)ev.z) * iv;                             \
        wo[3] = bf2f((unsigned short)ev.w) * iv;                             \
        __builtin_nontemporal_store(wo, (f32x4*)(out1 + wbase + (size_t)(r) * SS + tid * 4)); \
    }

    VLOAD(0, 0); VLOAD(1, 1);

#pragma unroll
    for (int ti = 0; ti < 2; ++ti)
#pragma unroll
        for (int r = 0; r < 4; ++r) {
            float s = sums[ti][r];
            s += __shfl_xor(s, 1); s += __shfl_xor(s, 2);
            s += __shfl_xor(s, 4); s += __shfl_xor(s, 8);
            if (lq == 0) wsum[wv][ti * 16 + quad * 4 + r] = s;
        }
    __syncthreads();
    if (tid < 32) {
        float s = wsum[0][tid] + wsum[1][tid] + wsum[2][tid] + wsum[3][tid];
        inv_s[tid] = 1.0f / s;
    }
    VLOAD(2, 2); VLOAD(3, 3);
    __syncthreads();

    // ---- PV phase: rotation with w-output rows interleaved (32 rows, 4/group)
    VCOMP(0, 0); VLOAD(0, 4); WOUT(0);  WOUT(1);  WOUT(2);  WOUT(3);
    VCOMP(1, 1); VLOAD(1, 5); WOUT(4);  WOUT(5);  WOUT(6);  WOUT(7);
    VCOMP(2, 2); VLOAD(2, 6); WOUT(8);  WOUT(9);  WOUT(10); WOUT(11);
    VCOMP(3, 3); VLOAD(3, 7); WOUT(12); WOUT(13); WOUT(14); WOUT(15);
    VCOMP(0, 4); WOUT(16); WOUT(17); WOUT(18); WOUT(19);
    VCOMP(1, 5); WOUT(20); WOUT(21); WOUT(22); WOUT(23);
    VCOMP(2, 6); WOUT(24); WOUT(25); WOUT(26); WOUT(27);
    VCOMP(3, 7); WOUT(28); WOUT(29); WOUT(30); WOUT(31);
#undef VLOAD
#undef VCOMP
#undef WOUT

#pragma unroll
    for (int ti = 0; ti < 2; ++ti)
#pragma unroll
        for (int r = 0; r < 4; ++r) {
            int row = ti * 16 + quad * 4 + r;
            size_t o = (size_t)(b * SS + i0 + row) * 1024 + h * 64 + wv * 16 + lq;
            __builtin_nontemporal_store(mf8[ti][r] + racc[ti][r] * inv_s[row], out0 + o);
        }
}

extern "C" void kernel_launch(void* const* d_in, const int* in_sizes, int n_in,
                              void* d_out, int out_size, void* d_ws, size_t ws_size,
                              hipStream_t stream) {
    const float* m_feats = (const float*)d_in[0];
    const int*   mask    = (const int*)d_in[1];
    const float* W_c     = (const float*)d_in[2];
    const float* b_c     = (const float*)d_in[3];
    const float* W_v     = (const float*)d_in[4];
    const float* b_v     = (const float*)d_in[5];

    float* out0 = (float*)d_out;                       // updated_m: 4*1024*1024
    float* out1 = out0 + (size_t)NB * SS * 1024;       // w: 4*16*1024*1024

    unsigned short* mf_bf = (unsigned short*)d_ws;                 // 4096*1024
    unsigned short* WT    = mf_bf + (size_t)4096 * 1024;           // 3072*1024
    unsigned short* kq    = WT + (size_t)3072 * 1024;              // 4096*2048
    unsigned short* mvT   = kq + (size_t)4096 * 2048;              // 4096*1024 [b][h][d][j]

    prep<<<dim3(5120), dim3(256), 0, stream>>>(m_feats, mf_bf, W_v, W_c, WT);
    gemm_kqv<<<dim3(24, 32), dim3(256), 0, stream>>>(mf_bf, WT, b_v, b_c, kq, mvT);
    attn_kernel<<<dim3(2048), dim3(256), 0, stream>>>(kq, mvT, mask, m_feats, out0, out1);
}